// Round 3
// baseline (1374.735 us; speedup 1.0000x reference)
//
#include <hip/hip_runtime.h>

// CIN fused kernel, round 3: mfma_f32_32x32x16_f16, h-in-registers.
// GEMM: M = B*16 (m = batch*16+d), N = 128, K = i*64+j (layer-0 zero-padded).
// Block = 256 thr (4 waves), NB = 16 batches. Wave w owns batches w*4..w*4+4
// (2 m-tiles of 32 rows = 2 batches each) x full N=128 (4 n-tiles of 32).
// acc = 2x4 f32x16 = 128 VGPR. A[m][k] = x[nb,i,d]*h[nb,j,d] built in-reg:
// each lane needs only 16 h values per batch (4 half8 runs) -> registers for
// the whole layer; x is one ds_read_u16 per i-step. B-frags stream from L2
// in pre-swizzled frag order (prep kernel) -> NO K-loop barriers, no LDS B.
// Layer-0 K=16 sparsity: skip sub-chunks with empty (j>i, j<39) support
// (incl. all q=3: j>=48 -> zero filter): 84 of 156 k-steps.

#define F0N 39
#define NC16 156                              // K/16 per layer
#define LAYER_HALVES (NC16 * 4 * 64 * 8)      // 319488 f16 per layer

typedef _Float16 half8 __attribute__((ext_vector_type(8)));
typedef float f32x16 __attribute__((ext_vector_type(16)));

// ---- prep: swizzle filters into 32x32x16 B-fragment order, f16, coalesced ----
// fprep[l][c16][nt][lane][reg] = F_l[row(kg), nt*32 + (lane&31)],
// kg = c16*16 + (lane>>5)*8 + reg; layer0 row = i*39+j (j=kg&63, i=kg>>6), 0 if j>=39.
__global__ void prep_kernel(const float* __restrict__ f0,
                            const float* __restrict__ f1,
                            const float* __restrict__ f2,
                            _Float16* __restrict__ fprep) {
    int blk  = blockIdx.x;            // l*NC16 + c16
    int l    = blk / NC16;
    int c16  = blk - l * NC16;
    int t    = threadIdx.x;
    int nt   = t >> 6;
    int lane = t & 63;
    int hf   = lane >> 5;
    int n    = nt * 32 + (lane & 31);
    const float* f = (l == 0) ? f0 : ((l == 1) ? f1 : f2);
    half8 v;
    #pragma unroll
    for (int reg = 0; reg < 8; ++reg) {
        int kg = c16 * 16 + hf * 8 + reg;
        float x;
        if (l == 0) {
            int fi = kg >> 6, fj = kg & 63;
            x = (fj < F0N) ? f[(fi * F0N + fj) * 128 + n] : 0.0f;
        } else {
            x = f[(size_t)kg * 128 + n];
        }
        v[reg] = (_Float16)x;
    }
    *(half8*)&fprep[(size_t)l * LAYER_HALVES + (((c16 * 4 + nt) * 64 + lane) << 3)] = v;
}

__global__ __launch_bounds__(256, 2) void cin_mfma(
    const float* __restrict__ xin,     // (B, 624) fp32
    const _Float16* __restrict__ fprep,
    const float* __restrict__ wnn,     // (256)
    const float* __restrict__ bnn,     // (1)
    float* __restrict__ out)           // (B)
{
    __shared__ _Float16 hT[16 * 16 * 72] __attribute__((aligned(16)));  // [nb][d][j pad72] 36864 B
    __shared__ _Float16 xs[16 * 16 * 40] __attribute__((aligned(16)));  // [nb][d][i pad40] 20480 B
    __shared__ float outacc[16];

    const int t     = threadIdx.x;
    const int wave  = t >> 6;
    const int lane  = t & 63;
    const int hf    = lane >> 5;     // k-half within 16-chunk
    const int lane5 = lane & 31;
    const int dl    = lane & 15;     // d for A-side
    const int bt    = lane5 >> 4;    // A-side batch within 32-row tile
    const int wb0   = wave * 4;      // wave's first batch (local)
    const int b0    = blockIdx.x * 16;

    // zero hT (j-pad must be 0: layer-0 h-runs read j up to 63, x only defined j<39)
    for (int u = t; u < 2304; u += 256) ((uint4*)hT)[u] = uint4{0, 0, 0, 0};
    if (t < 16) outacc[t] = 0.0f;
    __syncthreads();

    // stage x0 -> hT (layer-0 hidden, [nb][d][j=i]) and xs ([nb][d][i])
    for (int u = t; u < 16 * F0N; u += 256) {
        int nb = u / F0N;
        int i  = u - nb * F0N;
        const float* src = xin + (size_t)(b0 + nb) * 624 + i * 16;
        #pragma unroll
        for (int q = 0; q < 4; ++q) {
            float4 v = *(const float4*)(src + q * 4);
            int d = q * 4;
            hT[(nb * 16 + d + 0) * 72 + i] = (_Float16)v.x;
            hT[(nb * 16 + d + 1) * 72 + i] = (_Float16)v.y;
            hT[(nb * 16 + d + 2) * 72 + i] = (_Float16)v.z;
            hT[(nb * 16 + d + 3) * 72 + i] = (_Float16)v.w;
            xs[(nb * 16 + d + 0) * 40 + i] = (_Float16)v.x;
            xs[(nb * 16 + d + 1) * 40 + i] = (_Float16)v.y;
            xs[(nb * 16 + d + 2) * 40 + i] = (_Float16)v.z;
            xs[(nb * 16 + d + 3) * 40 + i] = (_Float16)v.w;
        }
    }
    __syncthreads();

    for (int layer = 0; layer < 3; ++layer) {
        // ---- load this layer's h into registers: 16 j-values per lane per batch ----
        // lane's A rows: m = lane5 -> batch nbL = wb0 + mt*2 + bt, d = dl.
        // j runs: r*16 + hf*8 .. +8 for r = 0..3.
        half8 hreg[2][4];
        #pragma unroll
        for (int mt = 0; mt < 2; ++mt) {
            int base = ((wb0 + mt * 2 + bt) * 16 + dl) * 72 + hf * 8;
            #pragma unroll
            for (int r = 0; r < 4; ++r)
                hreg[mt][r] = *(const half8*)&hT[base + r * 16];
        }
        __syncthreads();   // h-regs loaded everywhere before epilogue may overwrite hT

        f32x16 acc[2][4];
        #pragma unroll
        for (int mt = 0; mt < 2; ++mt)
            #pragma unroll
            for (int nt = 0; nt < 4; ++nt)
                #pragma unroll
                for (int e = 0; e < 16; ++e) acc[mt][nt][e] = 0.0f;

        const _Float16* fpl = fprep + (size_t)layer * LAYER_HALVES;

        if (layer == 0) {
            // K = i*64+j, j>i, j<39. Sub-chunk (i,q): j in [q*16, q*16+16).
            // Useful iff i <= min(q*16+14, 37); q=3 never (j>=48 -> zero filter).
            for (int i = 0; i < 38; ++i) {
                const int q0     = i >> 4;
                const int qstart = ((i & 15) == 15) ? q0 + 1 : q0;
                _Float16 xv2[2];
                #pragma unroll
                for (int mt = 0; mt < 2; ++mt)
                    xv2[mt] = (_Float16)2.0f *
                              xs[((wb0 + mt * 2 + bt) * 16 + dl) * 40 + i];
                for (int q = qstart; q <= 2; ++q) {
                    const int c16 = i * 4 + q;
                    half8 Bf[4];
                    #pragma unroll
                    for (int nt = 0; nt < 4; ++nt)
                        Bf[nt] = *(const half8*)(fpl + (((c16 * 4 + nt) * 64 + lane) << 3));
                    half8 Af[2];
                    if (q == q0) {   // partial: mask j<=i to zero
                        const int j0 = q * 16 + hf * 8;
                        #pragma unroll
                        for (int mt = 0; mt < 2; ++mt) {
                            half8 a;
                            #pragma unroll
                            for (int reg = 0; reg < 8; ++reg)
                                a[reg] = (j0 + reg > i) ? xv2[mt] : (_Float16)0.0f;
                            Af[mt] = hreg[mt][q] * a;
                        }
                    } else {
                        #pragma unroll
                        for (int mt = 0; mt < 2; ++mt)
                            Af[mt] = hreg[mt][q] * xv2[mt];
                    }
                    #pragma unroll
                    for (int mt = 0; mt < 2; ++mt)
                        #pragma unroll
                        for (int nt = 0; nt < 4; ++nt)
                            acc[mt][nt] = __builtin_amdgcn_mfma_f32_32x32x16_f16(
                                Af[mt], Bf[nt], acc[mt][nt], 0, 0, 0);
                }
            }
        } else {
            for (int ii = 0; ii < F0N; ++ii) {
                _Float16 xv[2];
                #pragma unroll
                for (int mt = 0; mt < 2; ++mt)
                    xv[mt] = xs[((wb0 + mt * 2 + bt) * 16 + dl) * 40 + ii];
                #pragma unroll
                for (int q = 0; q < 4; ++q) {
                    const int c16 = ii * 4 + q;
                    half8 Bf[4];
                    #pragma unroll
                    for (int nt = 0; nt < 4; ++nt)
                        Bf[nt] = *(const half8*)(fpl + (((c16 * 4 + nt) * 64 + lane) << 3));
                    half8 Af[2];
                    #pragma unroll
                    for (int mt = 0; mt < 2; ++mt)
                        Af[mt] = hreg[mt][q] * xv[mt];
                    #pragma unroll
                    for (int mt = 0; mt < 2; ++mt)
                        #pragma unroll
                        for (int nt = 0; nt < 4; ++nt)
                            acc[mt][nt] = __builtin_amdgcn_mfma_f32_32x32x16_f16(
                                Af[mt], Bf[nt], acc[mt][nt], 0, 0, 0);
                }
            }
        }

        // ---- epilogue ----
        // C/D layout: col n = nt*32 + lane5; row = (reg&3) + 8*(reg>>2) + 4*hf;
        // batch_in_tile = reg>>3, d = (reg&3) + 8*((reg>>2)&1) + 4*hf.
        const int catbase = (layer == 2) ? 128 : ((layer == 0) ? -64 : 0);
        #pragma unroll
        for (int mt = 0; mt < 2; ++mt) {
            const int nb0 = wb0 + mt * 2;
            float cm0 = 0.0f, cm1 = 0.0f;
            #pragma unroll
            for (int nt = 0; nt < 4; ++nt) {
                float r[16];
                #pragma unroll
                for (int reg = 0; reg < 16; ++reg)
                    r[reg] = fmaxf(acc[mt][nt][reg], 0.0f);
                if (layer < 2 && nt < 2) {         // next hidden: cols 0..63
                    const int j = nt * 32 + lane5;
                    #pragma unroll
                    for (int reg = 0; reg < 16; ++reg) {
                        int nb = nb0 + (reg >> 3);
                        int d  = (reg & 3) + 8 * ((reg >> 2) & 1) + 4 * hf;
                        hT[(nb * 16 + d) * 72 + j] = (_Float16)r[reg];
                    }
                }
                if (layer == 2 || nt >= 2) {       // direct-out readout
                    const float w = 1.0f + wnn[catbase + nt * 32 + lane5];
                    float s0 = ((r[0] + r[1]) + (r[2] + r[3])) +
                               ((r[4] + r[5]) + (r[6] + r[7]));
                    float s1 = ((r[8] + r[9]) + (r[10] + r[11])) +
                               ((r[12] + r[13]) + (r[14] + r[15]));
                    s0 += __shfl_xor(s0, 32, 64);  // combine hf halves (full d-sum)
                    s1 += __shfl_xor(s1, 32, 64);
                    cm0 = fmaf(s0, w, cm0);
                    cm1 = fmaf(s1, w, cm1);
                }
            }
            #pragma unroll
            for (int sh = 16; sh >= 1; sh >>= 1) {
                cm0 += __shfl_xor(cm0, sh, 64);
                cm1 += __shfl_xor(cm1, sh, 64);
            }
            if (lane == 0) {
                atomicAdd(&outacc[nb0], cm0);
                atomicAdd(&outacc[nb0 + 1], cm1);
            }
        }
        __syncthreads();   // hT(next hidden) + outacc visible
    }

    if (t < 16) out[b0 + t] = outacc[t] + bnn[0];
}

extern "C" void kernel_launch(void* const* d_in, const int* in_sizes, int n_in,
                              void* d_out, int out_size, void* d_ws, size_t ws_size,
                              hipStream_t stream) {
    const float* xin = (const float*)d_in[0];
    const float* f0g = (const float*)d_in[1];
    const float* f1g = (const float*)d_in[2];
    const float* f2g = (const float*)d_in[3];
    const float* wnn = (const float*)d_in[4];
    const float* bnn = (const float*)d_in[5];
    float* out = (float*)d_out;
    _Float16* fprep = (_Float16*)d_ws;   // 3 * 319488 * 2 B = 1.83 MB

    prep_kernel<<<3 * NC16, 256, 0, stream>>>(f0g, f1g, f2g, fprep);

    const int B = in_sizes[0] / 624;     // 8192
    cin_mfma<<<B / 16, 256, 0, stream>>>(xin, fprep, wnn, bnn, out);
}

// Round 4
// 253.351 us; speedup vs baseline: 5.4262x; 5.4262x over previous
//
#include <hip/hip_runtime.h>

// CIN fused kernel, round 4: mfma_f32_32x32x16_f16, h-in-registers,
// ALL register-array indices compile-time constant (round 3's dynamic q-loop
// spilled hreg+acc to scratch: WRITE_SIZE 32KB->18MB, MfmaUtil 6%).
// GEMM: M = B*16 (m = batch*16+d), N = 128, K = i*64+j (layer-0 zero-padded).
// Block = 256 thr (4 waves), NB = 16 batches. Wave w: batches w*4..w*4+4
// (2 m-tiles of 32 rows) x full N=128 (4 n-tiles). acc = 2x4 f32x16 (AGPR).
// B-frags stream from L2 in pre-swizzled frag order -> no K-loop barriers.
// Layer-0 K=16 sparsity via three static i-ranges: 84 of 156 k-steps.

#define F0N 39
#define NC16 156                              // K/16 per layer
#define LAYER_HALVES (NC16 * 4 * 64 * 8)      // 319488 f16 per layer

typedef _Float16 half8 __attribute__((ext_vector_type(8)));
typedef float f32x16 __attribute__((ext_vector_type(16)));

// ---- prep: swizzle filters into 32x32x16 B-fragment order, f16 ----
// fprep[l][c16][nt][lane][reg] = F_l[row(kg), nt*32 + (lane&31)],
// kg = c16*16 + (lane>>5)*8 + reg; layer0 row = i*39+j (j=kg&63), 0 if j>=39.
__global__ void prep_kernel(const float* __restrict__ f0,
                            const float* __restrict__ f1,
                            const float* __restrict__ f2,
                            _Float16* __restrict__ fprep) {
    int blk  = blockIdx.x;            // l*NC16 + c16
    int l    = blk / NC16;
    int c16  = blk - l * NC16;
    int t    = threadIdx.x;
    int nt   = t >> 6;
    int lane = t & 63;
    int hf   = lane >> 5;
    int n    = nt * 32 + (lane & 31);
    const float* f = (l == 0) ? f0 : ((l == 1) ? f1 : f2);
    half8 v;
    #pragma unroll
    for (int reg = 0; reg < 8; ++reg) {
        int kg = c16 * 16 + hf * 8 + reg;
        float x;
        if (l == 0) {
            int fi = kg >> 6, fj = kg & 63;
            x = (fj < F0N) ? f[(fi * F0N + fj) * 128 + n] : 0.0f;
        } else {
            x = f[(size_t)kg * 128 + n];
        }
        v[reg] = (_Float16)x;
    }
    *(half8*)&fprep[(size_t)l * LAYER_HALVES + (((c16 * 4 + nt) * 64 + lane) << 3)] = v;
}

// One K=16 step, Q is a LITERAL (keeps hreg indexing static).
#define LOAD_BF(C16)                                                          \
    half8 Bf[4];                                                              \
    {                                                                         \
        _Pragma("unroll")                                                     \
        for (int nt = 0; nt < 4; ++nt)                                        \
            Bf[nt] = *(const half8*)(fpl + ((((C16) * 4 + nt) * 64 + lane) << 3)); \
    }

#define DO_MFMA()                                                             \
    {                                                                         \
        _Pragma("unroll")                                                     \
        for (int mt = 0; mt < 2; ++mt)                                        \
            _Pragma("unroll")                                                 \
            for (int nt = 0; nt < 4; ++nt)                                    \
                acc[mt][nt] = __builtin_amdgcn_mfma_f32_32x32x16_f16(         \
                    Af[mt], Bf[nt], acc[mt][nt], 0, 0, 0);                    \
    }

#define FULL_STEP(Q)                                                          \
    do {                                                                      \
        LOAD_BF(i * 4 + (Q));                                                 \
        half8 Af[2];                                                          \
        _Pragma("unroll")                                                     \
        for (int mt = 0; mt < 2; ++mt) Af[mt] = hreg[mt][(Q)] * xv2[mt];      \
        DO_MFMA();                                                            \
    } while (0)

// partial: zero elements with j <= i (j = Q*16 + hf*8 + reg)
#define PART_STEP(Q)                                                          \
    do {                                                                      \
        LOAD_BF(i * 4 + (Q));                                                 \
        const int j0 = (Q) * 16 + hf * 8;                                     \
        half8 msk;                                                            \
        _Pragma("unroll")                                                     \
        for (int reg = 0; reg < 8; ++reg)                                     \
            msk[reg] = (j0 + reg > i) ? (_Float16)1.0f : (_Float16)0.0f;      \
        half8 Af[2];                                                          \
        _Pragma("unroll")                                                     \
        for (int mt = 0; mt < 2; ++mt) Af[mt] = hreg[mt][(Q)] * (msk * xv2[mt]); \
        DO_MFMA();                                                            \
    } while (0)

__global__ __launch_bounds__(256, 2) void cin_mfma(
    const float* __restrict__ xin,     // (B, 624) fp32
    const _Float16* __restrict__ fprep,
    const float* __restrict__ wnn,     // (256)
    const float* __restrict__ bnn,     // (1)
    float* __restrict__ out)           // (B)
{
    __shared__ _Float16 hT[16 * 16 * 72] __attribute__((aligned(16)));  // [nb][d][j pad72]
    __shared__ _Float16 xs[16 * 16 * 40] __attribute__((aligned(16)));  // [nb][d][i pad40]
    __shared__ float outacc[16];

    const int t     = threadIdx.x;
    const int wave  = t >> 6;
    const int lane  = t & 63;
    const int hf    = lane >> 5;     // k-half within 16-chunk
    const int lane5 = lane & 31;
    const int dl    = lane & 15;     // d for A-side
    const int bt    = lane5 >> 4;    // A-side batch within 32-row tile
    const int wb0   = wave * 4;      // wave's first batch (local)
    const int b0    = blockIdx.x * 16;

    // zero hT (j-pad must be 0: layer-0 h-runs read j up to 63)
    for (int u = t; u < 2304; u += 256) ((uint4*)hT)[u] = uint4{0, 0, 0, 0};
    if (t < 16) outacc[t] = 0.0f;
    __syncthreads();

    // stage x0 -> hT (layer-0 hidden, [nb][d][j=i]) and xs ([nb][d][i])
    for (int u = t; u < 16 * F0N; u += 256) {
        int nb = u / F0N;
        int i  = u - nb * F0N;
        const float* src = xin + (size_t)(b0 + nb) * 624 + i * 16;
        #pragma unroll
        for (int q = 0; q < 4; ++q) {
            float4 v = *(const float4*)(src + q * 4);
            int d = q * 4;
            hT[(nb * 16 + d + 0) * 72 + i] = (_Float16)v.x;
            hT[(nb * 16 + d + 1) * 72 + i] = (_Float16)v.y;
            hT[(nb * 16 + d + 2) * 72 + i] = (_Float16)v.z;
            hT[(nb * 16 + d + 3) * 72 + i] = (_Float16)v.w;
            xs[(nb * 16 + d + 0) * 40 + i] = (_Float16)v.x;
            xs[(nb * 16 + d + 1) * 40 + i] = (_Float16)v.y;
            xs[(nb * 16 + d + 2) * 40 + i] = (_Float16)v.z;
            xs[(nb * 16 + d + 3) * 40 + i] = (_Float16)v.w;
        }
    }
    __syncthreads();

    for (int layer = 0; layer < 3; ++layer) {
        // lane's A rows: m = lane5 -> batch wb0 + mt*2 + bt, d = dl.
        // j runs r*16 + hf*8 .. +8 for r = 0..3 -> 4 half8 per batch.
        half8 hreg[2][4];
        #pragma unroll
        for (int mt = 0; mt < 2; ++mt) {
            int base = ((wb0 + mt * 2 + bt) * 16 + dl) * 72 + hf * 8;
            #pragma unroll
            for (int r = 0; r < 4; ++r)
                hreg[mt][r] = *(const half8*)&hT[base + r * 16];
        }
        __syncthreads();   // h-regs loaded before epilogue may overwrite hT

        f32x16 acc[2][4];
        #pragma unroll
        for (int mt = 0; mt < 2; ++mt)
            #pragma unroll
            for (int nt = 0; nt < 4; ++nt)
                #pragma unroll
                for (int e = 0; e < 16; ++e) acc[mt][nt][e] = 0.0f;

        const _Float16* fpl = fprep + (size_t)layer * LAYER_HALVES;
        const int xrow0 = ((wb0 + bt) * 16 + dl) * 40;
        const int xrow1 = ((wb0 + 2 + bt) * 16 + dl) * 40;

        if (layer == 0) {
            // K = i*64+j, j>i, j<39 (j>=39 -> zero filter, harmless).
            _Float16 xv2[2];
            // i in [0,16): q0 partial (skip i==15), q1 full, q2 full
            for (int i = 0; i < 16; ++i) {
                xv2[0] = (_Float16)2.0f * xs[xrow0 + i];
                xv2[1] = (_Float16)2.0f * xs[xrow1 + i];
                if (i < 15) PART_STEP(0);
                FULL_STEP(1);
                FULL_STEP(2);
            }
            // i in [16,32): q1 partial (skip i==31), q2 full
            for (int i = 16; i < 32; ++i) {
                xv2[0] = (_Float16)2.0f * xs[xrow0 + i];
                xv2[1] = (_Float16)2.0f * xs[xrow1 + i];
                if (i < 31) PART_STEP(1);
                FULL_STEP(2);
            }
            // i in [32,38): q2 partial
            for (int i = 32; i < 38; ++i) {
                xv2[0] = (_Float16)2.0f * xs[xrow0 + i];
                xv2[1] = (_Float16)2.0f * xs[xrow1 + i];
                PART_STEP(2);
            }
        } else {
            _Float16 xv2[2];
            for (int i = 0; i < F0N; ++i) {
                xv2[0] = xs[xrow0 + i];
                xv2[1] = xs[xrow1 + i];
                FULL_STEP(0);
                FULL_STEP(1);
                FULL_STEP(2);
                FULL_STEP(3);
            }
        }

        // ---- epilogue ----
        // C/D layout: col n = nt*32 + lane5; row = (reg&3) + 8*(reg>>2) + 4*hf;
        // batch_in_tile = reg>>3, d = (reg&3) + 8*((reg>>2)&1) + 4*hf.
        const int catbase = (layer == 2) ? 128 : ((layer == 0) ? -64 : 0);
        #pragma unroll
        for (int mt = 0; mt < 2; ++mt) {
            const int nb0 = wb0 + mt * 2;
            float cm0 = 0.0f, cm1 = 0.0f;
            #pragma unroll
            for (int nt = 0; nt < 4; ++nt) {
                float r[16];
                #pragma unroll
                for (int reg = 0; reg < 16; ++reg)
                    r[reg] = fmaxf(acc[mt][nt][reg], 0.0f);
                if (layer < 2 && nt < 2) {         // next hidden: cols 0..63
                    const int j = nt * 32 + lane5;
                    #pragma unroll
                    for (int reg = 0; reg < 16; ++reg) {
                        int nb = nb0 + (reg >> 3);
                        int d  = (reg & 3) + 8 * ((reg >> 2) & 1) + 4 * hf;
                        hT[(nb * 16 + d) * 72 + j] = (_Float16)r[reg];
                    }
                }
                if (layer == 2 || nt >= 2) {       // direct-out readout
                    const float w = 1.0f + wnn[catbase + nt * 32 + lane5];
                    float s0 = ((r[0] + r[1]) + (r[2] + r[3])) +
                               ((r[4] + r[5]) + (r[6] + r[7]));
                    float s1 = ((r[8] + r[9]) + (r[10] + r[11])) +
                               ((r[12] + r[13]) + (r[14] + r[15]));
                    s0 += __shfl_xor(s0, 32, 64);  // combine hf halves (full d-sum)
                    s1 += __shfl_xor(s1, 32, 64);
                    cm0 = fmaf(s0, w, cm0);
                    cm1 = fmaf(s1, w, cm1);
                }
            }
            #pragma unroll
            for (int sh = 16; sh >= 1; sh >>= 1) {
                cm0 += __shfl_xor(cm0, sh, 64);
                cm1 += __shfl_xor(cm1, sh, 64);
            }
            if (lane == 0) {
                atomicAdd(&outacc[nb0], cm0);
                atomicAdd(&outacc[nb0 + 1], cm1);
            }
        }
        __syncthreads();   // hT(next hidden) + outacc visible
    }

    if (t < 16) out[b0 + t] = outacc[t] + bnn[0];
}

extern "C" void kernel_launch(void* const* d_in, const int* in_sizes, int n_in,
                              void* d_out, int out_size, void* d_ws, size_t ws_size,
                              hipStream_t stream) {
    const float* xin = (const float*)d_in[0];
    const float* f0g = (const float*)d_in[1];
    const float* f1g = (const float*)d_in[2];
    const float* f2g = (const float*)d_in[3];
    const float* wnn = (const float*)d_in[4];
    const float* bnn = (const float*)d_in[5];
    float* out = (float*)d_out;
    _Float16* fprep = (_Float16*)d_ws;   // 3 * 319488 * 2 B = 1.83 MB

    prep_kernel<<<3 * NC16, 256, 0, stream>>>(f0g, f1g, f2g, fprep);

    const int B = in_sizes[0] / 624;     // 8192
    cin_mfma<<<B / 16, 256, 0, stream>>>(xin, fprep, wnn, bnn, out);
}